// Round 7
// baseline (968.891 us; speedup 1.0000x reference)
//
#include <hip/hip_runtime.h>
#include <hip/hip_cooperative_groups.h>

namespace cg = cooperative_groups;

// ===========================================================================
// 2-node graph:
//   coeff_k  (cooperative, 512 blocks x 256 thr, 9 grid.sync phases):
//     conv1 -> conv2 -> conv3 -> conv4 -> (l1||g1) -> (loc||g2) -> fc3 ->
//     fc4 -> fc5 -> fusion+pointwise grid
//   guide_slice_row_k (2048 blocks): guide + trilinear slice + apply.
// Layouts: low-res chain HWC; bilateral grid cell-major [N][8][16][16][12].
// ===========================================================================

struct CoeffParams {
    const float *lowres;
    const float *sw1, *sb1, *sw2, *sb2, *sw3, *sb3, *sw4, *sb4;
    const float *gw1, *gb1, *gw2, *gb2;
    const float *fw3, *fb3, *fw4, *fb4, *fw5, *fb5;
    const float *lw1, *lb1, *lw2, *pw, *pb;
    float *x1, *x2, *x3, *splat, *g1, *g2, *fc3o, *s4g, *glob, *l1, *loc, *gridc;
};

// ---------------------------------------------------------------------------
// One wave-task of an HWC conv with lane = input channel (CIN<=64).
// Task wt covers OPW consecutive HWC outputs starting at wt*OPW.
// ---------------------------------------------------------------------------
template <int CIN>
__device__ __forceinline__ void convw_task(const float* __restrict__ in,
                                           const float* __restrict__ w,
                                           const float* __restrict__ b,
                                           float* __restrict__ out,
                                           int wt, int lane,
                                           int Hin, int Win, int Cout,
                                           int Hout, int Wout, int stride,
                                           int do_relu, int total)
{
    constexpr int OPW = 64 / CIN;
    int sub = lane / CIN;
    int cl  = lane % CIN;
    int o   = wt * OPW + sub;

    float acc = 0.0f;
    if (o < total) {
        int co  = o % Cout;
        int pix = o / Cout;
        int ow  = pix % Wout;
        int oh  = (pix / Wout) % Hout;
        int n   = pix / (Wout * Hout);
        const float* wb = w + ((size_t)co * CIN + cl) * 9;
        #pragma unroll
        for (int kh = 0; kh < 3; ++kh) {
            int ih = oh * stride - 1 + kh;
            if (ih < 0 || ih >= Hin) continue;
            const float* ib = in + (((size_t)(n * Hin + ih)) * Win) * CIN + cl;
            #pragma unroll
            for (int kw = 0; kw < 3; ++kw) {
                int iw = ow * stride - 1 + kw;
                if (iw < 0 || iw >= Win) continue;
                acc = fmaf(ib[(size_t)iw * CIN], wb[kh * 3 + kw], acc);
            }
        }
    }
    #pragma unroll
    for (int off = CIN / 2; off >= 1; off >>= 1)
        acc += __shfl_xor(acc, off, 64);
    if (o < total && cl == 0) {
        if (b) acc += b[o % Cout];
        if (do_relu) acc = fmaxf(acc, 0.0f);
        out[o] = acc;
    }
}

// CIN=64 variant with n-local pointers (used for l1/g1/loc/g2 phases).
__device__ __forceinline__ void convw64_one(const float* __restrict__ in,
                                            const float* __restrict__ wgt,
                                            const float* __restrict__ bias,
                                            float* __restrict__ out,
                                            int o, int Hin, int Win, int Wout,
                                            int stride, bool relu, int lane)
{
    int co  = o & 63;
    int pix = o >> 6;
    int ow  = pix % Wout;
    int oh  = pix / Wout;
    const float* wb = wgt + ((size_t)co * 64 + lane) * 9;
    float acc = 0.0f;
    #pragma unroll
    for (int kh = 0; kh < 3; ++kh) {
        int ih = oh * stride - 1 + kh;
        if (ih < 0 || ih >= Hin) continue;
        const float* ib = in + ((size_t)ih * Win) * 64 + lane;
        #pragma unroll
        for (int kw = 0; kw < 3; ++kw) {
            int iw = ow * stride - 1 + kw;
            if (iw < 0 || iw >= Win) continue;
            acc = fmaf(ib[(size_t)iw * 64], wb[kh * 3 + kw], acc);
        }
    }
    #pragma unroll
    for (int off = 32; off >= 1; off >>= 1)
        acc += __shfl_xor(acc, off, 64);
    if (lane == 0) {
        if (bias) acc += bias[co];
        if (relu) acc = fmaxf(acc, 0.0f);
        out[o] = acc;
    }
}

// ---------------------------------------------------------------------------
// The cooperative coefficient-path kernel. 512 blocks x 256 threads.
// ---------------------------------------------------------------------------
__global__ void __launch_bounds__(256) coeff_k(CoeffParams P)
{
    cg::grid_group grid = cg::this_grid();
    const int tid   = blockIdx.x * 256 + threadIdx.x;   // 0..131071
    const int lane  = threadIdx.x & 63;
    const int gwave = tid >> 6;                         // 0..2047

    // ---- P1: conv1  lowres CHW [2,3,256,256] -> x1 HWC [2,128,128,8] ----
    for (int t = tid; t < 262144; t += 131072) {
        int co = t & 7;
        int ow = (t >> 3) & 127;
        int oh = (t >> 10) & 127;
        int n  = t >> 17;
        float acc = P.sb1[co];
        #pragma unroll
        for (int ci = 0; ci < 3; ++ci) {
            const float* ib = P.lowres + ((size_t)(n * 3 + ci)) * 65536;
            const float* wb = P.sw1 + ((size_t)co * 3 + ci) * 9;
            #pragma unroll
            for (int kh = 0; kh < 3; ++kh) {
                int ih = oh * 2 - 1 + kh;
                if (ih < 0 || ih >= 256) continue;
                #pragma unroll
                for (int kw = 0; kw < 3; ++kw) {
                    int iw = ow * 2 - 1 + kw;
                    if (iw < 0 || iw >= 256) continue;
                    acc = fmaf(ib[ih * 256 + iw], wb[kh * 3 + kw], acc);
                }
            }
        }
        P.x1[t] = fmaxf(acc, 0.0f);
    }
    __threadfence();
    grid.sync();

    // ---- P2: conv2  x1 -> x2 HWC [2,64,64,16] (CIN=8, 16384 tasks) ----
    for (int wt = gwave; wt < 16384; wt += 2048)
        convw_task<8>(P.x1, P.sw2, P.sb2, P.x2, wt, lane,
                      128, 128, 16, 64, 64, 2, 1, 131072);
    __threadfence();
    grid.sync();

    // ---- P3: conv3  x2 -> x3 HWC [2,32,32,32] (CIN=16, 16384 tasks) ----
    for (int wt = gwave; wt < 16384; wt += 2048)
        convw_task<16>(P.x2, P.sw3, P.sb3, P.x3, wt, lane,
                       64, 64, 32, 32, 32, 2, 1, 65536);
    __threadfence();
    grid.sync();

    // ---- P4: conv4  x3 -> splat HWC [2,16,16,64] (CIN=32, 16384 tasks) ----
    for (int wt = gwave; wt < 16384; wt += 2048)
        convw_task<32>(P.x3, P.sw4, P.sb4, P.splat, wt, lane,
                       32, 32, 64, 16, 16, 2, 1, 32768);
    __threadfence();
    grid.sync();

    // ---- P5: l1 || g1 (40960 CIN=64 tasks) ----
    for (int t = gwave; t < 40960; t += 2048) {
        if (t < 32768) {
            int n = t >> 14, o = t & 16383;
            convw64_one(P.splat + (size_t)n * 16384, P.lw1, P.lb1,
                        P.l1 + (size_t)n * 16384, o, 16, 16, 16, 1, true, lane);
        } else {
            int t2 = t - 32768;
            int n = t2 >> 12, o = t2 & 4095;
            convw64_one(P.splat + (size_t)n * 16384, P.gw1, P.gb1,
                        P.g1 + (size_t)n * 4096, o, 16, 16, 8, 2, true, lane);
        }
    }
    __threadfence();
    grid.sync();

    // ---- P6: loc || g2 (34816 tasks) ----
    for (int t = gwave; t < 34816; t += 2048) {
        if (t < 32768) {
            int n = t >> 14, o = t & 16383;
            convw64_one(P.l1 + (size_t)n * 16384, P.lw2, nullptr,
                        P.loc + (size_t)n * 16384, o, 16, 16, 16, 1, false, lane);
        } else {
            int t2 = t - 32768;
            int n = t2 >> 10, o = t2 & 1023;
            convw64_one(P.g1 + (size_t)n * 4096, P.gw2, P.gb2,
                        P.g2 + (size_t)n * 1024, o, 8, 8, 4, 2, true, lane);
        }
    }
    __threadfence();
    grid.sync();

    // ---- P7: fc3 (512 wave-tasks; g2 HWC -> CHW permuted input) ----
    if (gwave < 512) {
        int o = gwave & 255;
        int n = gwave >> 8;
        const float* g2n = P.g2 + (size_t)n * 1024;
        const float* wb  = P.fw3 + (size_t)o * 1024;
        float acc = 0.0f;
        #pragma unroll
        for (int i = 0; i < 16; ++i) {
            int j = lane + i * 64;
            acc = fmaf(g2n[(j & 15) * 64 + (j >> 4)], wb[j], acc);
        }
        #pragma unroll
        for (int off = 32; off >= 1; off >>= 1) acc += __shfl_xor(acc, off, 64);
        if (lane == 0) P.fc3o[gwave] = fmaxf(acc + P.fb3[o], 0.0f);
    }
    __threadfence();
    grid.sync();

    // ---- P8: fc4 (256 wave-tasks) ----
    if (gwave < 256) {
        int o = gwave & 127;
        int n = gwave >> 7;
        const float* in = P.fc3o + (size_t)n * 256;
        const float* wb = P.fw4 + (size_t)o * 256;
        float acc = 0.0f;
        #pragma unroll
        for (int j = 0; j < 4; ++j)
            acc = fmaf(in[lane + j * 64], wb[lane + j * 64], acc);
        #pragma unroll
        for (int off = 32; off >= 1; off >>= 1) acc += __shfl_xor(acc, off, 64);
        if (lane == 0) P.s4g[gwave] = fmaxf(acc + P.fb4[o], 0.0f);
    }
    __threadfence();
    grid.sync();

    // ---- P9: fc5 (128 wave-tasks, no relu) ----
    if (gwave < 128) {
        int o = gwave & 63;
        int n = gwave >> 6;
        const float* in = P.s4g + (size_t)n * 128;
        const float* wb = P.fw5 + (size_t)o * 128;
        float acc = 0.0f;
        #pragma unroll
        for (int j = 0; j < 2; ++j)
            acc = fmaf(in[lane + j * 64], wb[lane + j * 64], acc);
        #pragma unroll
        for (int off = 32; off >= 1; off >>= 1) acc += __shfl_xor(acc, off, 64);
        if (lane == 0) P.glob[gwave] = acc + P.fb5[o];
    }
    __threadfence();
    grid.sync();

    // ---- P10: fusion + pointwise -> cell-major grid (49152 outputs) ----
    for (int t = tid; t < 49152; t += 131072) {
        int c = t % 12;
        int p = (t / 12) & 255;
        int z = (t / 3072) & 7;
        int n = t / 24576;
        int co = c * 8 + z;
        const float4* lp = (const float4*)(P.loc + ((size_t)n * 256 + p) * 64);
        const float4* gp = (const float4*)(P.glob + (size_t)n * 64);
        const float4* wp = (const float4*)(P.pw + (size_t)co * 64);
        float acc = P.pb[co];
        #pragma unroll
        for (int i = 0; i < 16; ++i) {
            float4 l = lp[i], g = gp[i], w = wp[i];
            acc = fmaf(fmaxf(l.x + g.x, 0.0f), w.x, acc);
            acc = fmaf(fmaxf(l.y + g.y, 0.0f), w.y, acc);
            acc = fmaf(fmaxf(l.z + g.z, 0.0f), w.z, acc);
            acc = fmaf(fmaxf(l.w + g.w, 0.0f), w.w, acc);
        }
        P.gridc[t] = acc;
    }
}

// ---------------------------------------------------------------------------
// Fused guide + slice + apply, one block per image row (256 thr x 4 px).
// y-interpolated grid staged in 6KB LDS; per-pixel bilinear (x,z) from LDS.
// ---------------------------------------------------------------------------
__global__ void guide_slice_row_k(const float* __restrict__ fullres,
                                  const float* __restrict__ gridc,
                                  const float* __restrict__ M,
                                  const float* __restrict__ Mb,
                                  const float* __restrict__ thr,
                                  const float* __restrict__ slopes,
                                  const float* __restrict__ gbias,
                                  float* __restrict__ out)
{
    const int W = 1024, H = 1024;
    __shared__ float ly[1536];              // [z][xn][c] = [8][16][12]

    int h = blockIdx.x & 1023;
    int n = blockIdx.x >> 10;

    float iy = fminf(fmaxf((float)h * (16.0f / (H - 1)) - 0.5f, 0.0f), 15.0f);
    float y0f = floorf(iy);
    float wy  = iy - y0f;
    int y0 = (int)y0f, y1 = min(y0 + 1, 15);

    const float* gn = gridc + (size_t)n * 24576;
    for (int i = threadIdx.x; i < 1536; i += 256) {
        int z   = i / 192;
        int rem = i - z * 192;
        float a = gn[z * 3072 + y0 * 192 + rem];
        float b = gn[z * 3072 + y1 * 192 + rem];
        ly[i] = fmaf(wy, b - a, a);
    }
    __syncthreads();

    int w0 = (int)threadIdx.x * 4;
    size_t plane = (size_t)H * W;
    size_t base  = (size_t)n * 3 * plane + (size_t)h * W + w0;
    float4 R  = *(const float4*)&fullres[base];
    float4 G  = *(const float4*)&fullres[base + plane];
    float4 Bc = *(const float4*)&fullres[base + 2 * plane];

    const float4* L = (const float4*)ly;

    float4 RR, GG, BB;
    float* rr = &RR.x; float* gg = &GG.x; float* bb = &BB.x;
    const float* rp = &R.x; const float* gp = &G.x; const float* bp = &Bc.x;

    #pragma unroll
    for (int p = 0; p < 4; ++p) {
        float r = rp[p], g = gp[p], bc = bp[p];
        int w = w0 + p;

        float gs = 0.0f;
        #pragma unroll
        for (int j = 0; j < 3; ++j) {
            float gj = Mb[j] + r * M[j] + g * M[3 + j] + bc * M[6 + j];
            float s = 0.0f;
            #pragma unroll
            for (int k = 0; k < 16; ++k)
                s = fmaf(slopes[j * 16 + k], fmaxf(gj - thr[j * 16 + k], 0.0f), s);
            gs += s;
        }
        float guide = fminf(fmaxf(gs * (1.0f / 3.0f) + gbias[0], 0.0f), 1.0f);

        float ix = fminf(fmaxf((float)w * (16.0f / (W - 1)) - 0.5f, 0.0f), 15.0f);
        float iz = fminf(fmaxf(8.0f * guide - 0.5f, 0.0f), 7.0f);
        float x0f = floorf(ix), z0f = floorf(iz);
        float wx = ix - x0f, wz = iz - z0f;
        int x0 = (int)x0f; int x1 = min(x0 + 1, 15);
        int z0 = (int)z0f; int z1 = min(z0 + 1, 7);
        float mx = 1.f - wx, mz = 1.f - wz;

        int n00 = (z0 * 16 + x0) * 3, n01 = (z0 * 16 + x1) * 3;
        int n10 = (z1 * 16 + x0) * 3, n11 = (z1 * 16 + x1) * 3;
        float W00 = mz * mx, W01 = mz * wx, W10 = wz * mx, W11 = wz * wx;

        float4 A0 = {0.f, 0.f, 0.f, 0.f}, A1 = A0, A2 = A0;
        auto nodeacc = [&](int nb, float wt) {
            float4 v0 = L[nb], v1 = L[nb + 1], v2 = L[nb + 2];
            A0.x = fmaf(wt, v0.x, A0.x); A0.y = fmaf(wt, v0.y, A0.y);
            A0.z = fmaf(wt, v0.z, A0.z); A0.w = fmaf(wt, v0.w, A0.w);
            A1.x = fmaf(wt, v1.x, A1.x); A1.y = fmaf(wt, v1.y, A1.y);
            A1.z = fmaf(wt, v1.z, A1.z); A1.w = fmaf(wt, v1.w, A1.w);
            A2.x = fmaf(wt, v2.x, A2.x); A2.y = fmaf(wt, v2.y, A2.y);
            A2.z = fmaf(wt, v2.z, A2.z); A2.w = fmaf(wt, v2.w, A2.w);
        };
        nodeacc(n00, W00);
        nodeacc(n01, W01);
        nodeacc(n10, W10);
        nodeacc(n11, W11);

        rr[p] = fmaf(r, A0.x, fmaf(g, A0.y, fmaf(bc, A0.z, A0.w)));
        gg[p] = fmaf(r, A1.x, fmaf(g, A1.y, fmaf(bc, A1.z, A1.w)));
        bb[p] = fmaf(r, A2.x, fmaf(g, A2.y, fmaf(bc, A2.z, A2.w)));
    }

    *(float4*)&out[base]             = RR;
    *(float4*)&out[base + plane]     = GG;
    *(float4*)&out[base + 2 * plane] = BB;
}

// ---------------------------------------------------------------------------
extern "C" void kernel_launch(void* const* d_in, const int* in_sizes, int n_in,
                              void* d_out, int out_size, void* d_ws, size_t ws_size,
                              hipStream_t stream)
{
    const float* lowres  = (const float*)d_in[0];
    const float* fullres = (const float*)d_in[1];

    float* ws = (float*)d_ws;
    CoeffParams P;
    P.lowres = lowres;
    P.sw1 = (const float*)d_in[2];  P.sb1 = (const float*)d_in[3];
    P.sw2 = (const float*)d_in[4];  P.sb2 = (const float*)d_in[5];
    P.sw3 = (const float*)d_in[6];  P.sb3 = (const float*)d_in[7];
    P.sw4 = (const float*)d_in[8];  P.sb4 = (const float*)d_in[9];
    P.gw1 = (const float*)d_in[10]; P.gb1 = (const float*)d_in[11];
    P.gw2 = (const float*)d_in[12]; P.gb2 = (const float*)d_in[13];
    P.fw3 = (const float*)d_in[14]; P.fb3 = (const float*)d_in[15];
    P.fw4 = (const float*)d_in[16]; P.fb4 = (const float*)d_in[17];
    P.fw5 = (const float*)d_in[18]; P.fb5 = (const float*)d_in[19];
    P.lw1 = (const float*)d_in[20]; P.lb1 = (const float*)d_in[21];
    P.lw2 = (const float*)d_in[22];
    P.pw  = (const float*)d_in[23]; P.pb  = (const float*)d_in[24];
    const float* M   = (const float*)d_in[25];
    const float* Mb  = (const float*)d_in[26];
    const float* thr = (const float*)d_in[27];
    const float* slp = (const float*)d_in[28];
    const float* gbias = (const float*)d_in[29];

    P.x1    = ws;              // [2][128][128][8]  = 262144
    P.x2    = P.x1 + 262144;   // [2][64][64][16]   = 131072
    P.x3    = P.x2 + 131072;   // [2][32][32][32]   = 65536
    P.splat = P.x3 + 65536;    // [2][16][16][64]   = 32768
    P.g1    = P.splat + 32768; // [2][8][8][64]     = 8192
    P.g2    = P.g1 + 8192;     // [2][4][4][64]     = 2048
    P.fc3o  = P.g2 + 2048;     // [2][256]
    P.s4g   = P.fc3o + 512;    // [2][128]
    P.glob  = P.s4g + 256;     // [2][64]
    P.l1    = P.glob + 128;    // [2][16][16][64]   = 32768
    P.loc   = P.l1 + 32768;    // [2][16][16][64]   = 32768
    P.gridc = P.loc + 32768;   // [2][8][16][16][12]= 49152

    void* args[] = { &P };
    hipLaunchCooperativeKernel((const void*)coeff_k, dim3(512), dim3(256),
                               args, 0, stream);

    guide_slice_row_k<<<2 * 1024, 256, 0, stream>>>(fullres, P.gridc, M, Mb,
        thr, slp, gbias, (float*)d_out);
}

// Round 8
// 132.896 us; speedup vs baseline: 7.2906x; 7.2906x over previous
//
#include <hip/hip_runtime.h>

// ===========================================================================
// R8: R6 structure (9 nodes, ~1us/node gap measured) + guide-LUT slice.
// Layouts: low-res chain HWC; bilateral grid cell-major [N][8][16][16][12].
// Transfer function sum_k s_k*relu(g-t_k) is piecewise-linear -> 512-bin
// {value,delta} LUT (exact between knots), built by conv1 block 0.
// LESSON (R7): grid.sync() on MI355X ~100us each — never for short phases.
// ===========================================================================

#define LUT_NB   512
#define LUT_LO   (-0.25f)
#define LUT_BIN  (1.5f / LUT_NB)
#define LUT_INV  (LUT_NB / 1.5f)

// ---------------------------------------------------------------------------
// conv1: lowres CHW [N,3,256,256] -> x1 HWC [N,128,128,8], stride 2, relu.
// Block 0 additionally builds the guide-transfer LUT (3 channels x 512 bins).
// ---------------------------------------------------------------------------
__global__ void conv1_lut_k(const float* __restrict__ in, const float* __restrict__ w,
                            const float* __restrict__ b,
                            const float* __restrict__ thr, const float* __restrict__ slp,
                            float* __restrict__ out, float2* __restrict__ lut)
{
    if (blockIdx.x == 0) {
        for (int e = threadIdx.x; e < 3 * LUT_NB; e += blockDim.x) {
            int j = e >> 9;           // channel
            int i = e & (LUT_NB - 1); // bin
            float xl = LUT_LO + i * LUT_BIN;
            float xh = xl + LUT_BIN;
            float a = 0.0f, c = 0.0f;
            #pragma unroll
            for (int k = 0; k < 16; ++k) {
                float tt = thr[j * 16 + k], ss = slp[j * 16 + k];
                a = fmaf(ss, fmaxf(xl - tt, 0.0f), a);
                c = fmaf(ss, fmaxf(xh - tt, 0.0f), c);
            }
            lut[e] = make_float2(a, c - a);
        }
    }

    int t = blockIdx.x * blockDim.x + threadIdx.x;
    const int total = 2 * 128 * 128 * 8;
    if (t >= total) return;
    int co = t & 7;
    int ow = (t >> 3) & 127;
    int oh = (t >> 10) & 127;
    int n  = t >> 17;

    float acc = b[co];
    #pragma unroll
    for (int ci = 0; ci < 3; ++ci) {
        const float* ib = in + ((size_t)(n * 3 + ci)) * 65536;
        const float* wb = w + ((size_t)co * 3 + ci) * 9;
        #pragma unroll
        for (int kh = 0; kh < 3; ++kh) {
            int ih = oh * 2 - 1 + kh;
            if (ih < 0 || ih >= 256) continue;
            #pragma unroll
            for (int kw = 0; kw < 3; ++kw) {
                int iw = ow * 2 - 1 + kw;
                if (iw < 0 || iw >= 256) continue;
                acc = fmaf(ib[ih * 256 + iw], wb[kh * 3 + kw], acc);
            }
        }
    }
    out[t] = fmaxf(acc, 0.0f);
}

// ---------------------------------------------------------------------------
// Wave conv, HWC in/out, lane = input channel, subgroup shuffle-reduce.
// ---------------------------------------------------------------------------
template <int CIN>
__global__ void convw_hwc_k(const float* __restrict__ in, const float* __restrict__ w,
                            const float* __restrict__ b, float* __restrict__ out,
                            int N, int Hin, int Win, int Cout, int Hout, int Wout,
                            int stride, int do_relu)
{
    constexpr int OPW = 64 / CIN;
    int lane = threadIdx.x & 63;
    int wid  = (blockIdx.x * blockDim.x + threadIdx.x) >> 6;
    int sub  = lane / CIN;
    int cl   = lane % CIN;
    int o    = wid * OPW + sub;
    int total = N * Hout * Wout * Cout;

    float acc = 0.0f;
    if (o < total) {
        int co  = o % Cout;
        int pix = o / Cout;
        int ow  = pix % Wout;
        int oh  = (pix / Wout) % Hout;
        int n   = pix / (Wout * Hout);
        const float* wb = w + ((size_t)co * CIN + cl) * 9;
        #pragma unroll
        for (int kh = 0; kh < 3; ++kh) {
            int ih = oh * stride - 1 + kh;
            if (ih < 0 || ih >= Hin) continue;
            const float* ib = in + (((size_t)(n * Hin + ih)) * Win) * CIN + cl;
            #pragma unroll
            for (int kw = 0; kw < 3; ++kw) {
                int iw = ow * stride - 1 + kw;
                if (iw < 0 || iw >= Win) continue;
                acc = fmaf(ib[(size_t)iw * CIN], wb[kh * 3 + kw], acc);
            }
        }
    }
    #pragma unroll
    for (int off = CIN / 2; off >= 1; off >>= 1)
        acc += __shfl_xor(acc, off, 64);

    if (o < total && cl == 0) {
        if (b) acc += b[o % Cout];
        if (do_relu) acc = fmaxf(acc, 0.0f);
        out[o] = acc;
    }
}

// ---------------------------------------------------------------------------
// One CIN=64 wave-conv output (lane = input channel). in/out n-local HWC.
// ---------------------------------------------------------------------------
__device__ __forceinline__ void convw64_one(const float* __restrict__ in,
                                            const float* __restrict__ wgt,
                                            const float* __restrict__ bias,
                                            float* __restrict__ out,
                                            int o, int Hin, int Win, int Wout,
                                            int stride, bool relu, int lane)
{
    int co  = o & 63;
    int pix = o >> 6;
    int ow  = pix % Wout;
    int oh  = pix / Wout;
    const float* wb = wgt + ((size_t)co * 64 + lane) * 9;
    float acc = 0.0f;
    #pragma unroll
    for (int kh = 0; kh < 3; ++kh) {
        int ih = oh * stride - 1 + kh;
        if (ih < 0 || ih >= Hin) continue;
        const float* ib = in + ((size_t)ih * Win) * 64 + lane;
        #pragma unroll
        for (int kw = 0; kw < 3; ++kw) {
            int iw = ow * stride - 1 + kw;
            if (iw < 0 || iw >= Win) continue;
            acc = fmaf(ib[(size_t)iw * 64], wb[kh * 3 + kw], acc);
        }
    }
    #pragma unroll
    for (int off = 32; off >= 1; off >>= 1)
        acc += __shfl_xor(acc, off, 64);
    if (lane == 0) {
        if (bias) acc += bias[co];
        if (relu) acc = fmaxf(acc, 0.0f);
        out[o] = acc;
    }
}

// ---------------------------------------------------------------------------
// l1 || g1 (both read splat). l1: 16x16 s1 relu; g1: ->8x8 s2 relu.
// ---------------------------------------------------------------------------
__global__ void l1_g1_k(const float* __restrict__ splat,
                        const float* __restrict__ lw1, const float* __restrict__ lb1,
                        const float* __restrict__ gw1, const float* __restrict__ gb1,
                        float* __restrict__ l1, float* __restrict__ g1)
{
    int lane = threadIdx.x & 63;
    int W = (blockIdx.x * blockDim.x + threadIdx.x) >> 6;
    if (W < 32768) {
        int n = W >> 14, o = W & 16383;
        convw64_one(splat + (size_t)n * 16384, lw1, lb1, l1 + (size_t)n * 16384,
                    o, 16, 16, 16, 1, true, lane);
    } else {
        int W2 = W - 32768;
        if (W2 >= 8192) return;
        int n = W2 >> 12, o = W2 & 4095;
        convw64_one(splat + (size_t)n * 16384, gw1, gb1, g1 + (size_t)n * 4096,
                    o, 16, 16, 8, 2, true, lane);
    }
}

// ---------------------------------------------------------------------------
// loc || g2. loc: conv(l1) no bias/relu; g2: 8x8->4x4 s2 relu.
// ---------------------------------------------------------------------------
__global__ void loc_g2_k(const float* __restrict__ l1, const float* __restrict__ lw2,
                         const float* __restrict__ g1, const float* __restrict__ gw2,
                         const float* __restrict__ gb2,
                         float* __restrict__ loc, float* __restrict__ g2)
{
    int lane = threadIdx.x & 63;
    int W = (blockIdx.x * blockDim.x + threadIdx.x) >> 6;
    if (W < 32768) {
        int n = W >> 14, o = W & 16383;
        convw64_one(l1 + (size_t)n * 16384, lw2, nullptr, loc + (size_t)n * 16384,
                    o, 16, 16, 16, 1, false, lane);
    } else {
        int W2 = W - 32768;
        if (W2 >= 2048) return;
        int n = W2 >> 10, o = W2 & 1023;
        convw64_one(g1 + (size_t)n * 4096, gw2, gb2, g2 + (size_t)n * 1024,
                    o, 8, 8, 4, 2, true, lane);
    }
}

// ---------------------------------------------------------------------------
// fc3: wave per output; g2 is HWC [N][16][64]; weights CHW-flat (j=c*16+p).
// ---------------------------------------------------------------------------
__global__ void fc3_wave_k(const float* __restrict__ g2, const float* __restrict__ w,
                           const float* __restrict__ b, float* __restrict__ out,
                           int N)
{
    int lane = threadIdx.x & 63;
    int wid  = (blockIdx.x * blockDim.x + threadIdx.x) >> 6;
    if (wid >= N * 256) return;
    int o = wid % 256;
    int n = wid / 256;
    const float* g2n = g2 + (size_t)n * 1024;
    const float* wb  = w + (size_t)o * 1024;
    float acc = 0.0f;
    #pragma unroll
    for (int i = 0; i < 16; ++i) {
        int j = lane + i * 64;
        acc = fmaf(g2n[(j & 15) * 64 + (j >> 4)], wb[j], acc);
    }
    #pragma unroll
    for (int off = 32; off >= 1; off >>= 1) acc += __shfl_xor(acc, off, 64);
    if (lane == 0) out[wid] = fmaxf(acc + b[o], 0.0f);
}

// ---------------------------------------------------------------------------
// fc4+fc5 (recomputed per block, weights L2-hot) + fusion + pointwise grid.
// 192 blocks x 256 thr; block's 256 outputs all share one n.
// ---------------------------------------------------------------------------
__global__ void fc45_fusion_k(const float* __restrict__ fc3o,
                              const float* __restrict__ fw4, const float* __restrict__ fb4,
                              const float* __restrict__ fw5, const float* __restrict__ fb5,
                              const float* __restrict__ loc,
                              const float* __restrict__ pw, const float* __restrict__ pb,
                              float* __restrict__ gridc)
{
    __shared__ float s4[128];
    __shared__ float globs[64];
    int t    = blockIdx.x * 256 + threadIdx.x;
    int n    = t / 24576;
    int lane = threadIdx.x & 63;
    int wv   = threadIdx.x >> 6;            // 4 waves
    const float* in = fc3o + (size_t)n * 256;

    #pragma unroll
    for (int k = 0; k < 32; ++k) {
        int o = wv * 32 + k;
        const float* wb = fw4 + (size_t)o * 256;
        float acc = 0.0f;
        #pragma unroll
        for (int j = 0; j < 4; ++j)
            acc = fmaf(in[lane + j * 64], wb[lane + j * 64], acc);
        #pragma unroll
        for (int off = 32; off >= 1; off >>= 1) acc += __shfl_xor(acc, off, 64);
        if (lane == 0) s4[o] = fmaxf(acc + fb4[o], 0.0f);
    }
    __syncthreads();
    #pragma unroll
    for (int k = 0; k < 16; ++k) {
        int o = wv * 16 + k;
        const float* wb = fw5 + (size_t)o * 128;
        float acc = 0.0f;
        #pragma unroll
        for (int j = 0; j < 2; ++j)
            acc = fmaf(s4[lane + j * 64], wb[lane + j * 64], acc);
        #pragma unroll
        for (int off = 32; off >= 1; off >>= 1) acc += __shfl_xor(acc, off, 64);
        if (lane == 0) globs[o] = acc + fb5[o];
    }
    __syncthreads();

    int c = t % 12;
    int p = (t / 12) & 255;
    int z = (t / 3072) & 7;
    int co = c * 8 + z;

    const float4* lp = (const float4*)(loc + ((size_t)n * 256 + p) * 64);
    const float4* gp = (const float4*)globs;
    const float4* wp = (const float4*)(pw + (size_t)co * 64);
    float acc = pb[co];
    #pragma unroll
    for (int i = 0; i < 16; ++i) {
        float4 l = lp[i], g = gp[i], w = wp[i];
        acc = fmaf(fmaxf(l.x + g.x, 0.0f), w.x, acc);
        acc = fmaf(fmaxf(l.y + g.y, 0.0f), w.y, acc);
        acc = fmaf(fmaxf(l.z + g.z, 0.0f), w.z, acc);
        acc = fmaf(fmaxf(l.w + g.w, 0.0f), w.w, acc);
    }
    gridc[t] = acc;
}

// ---------------------------------------------------------------------------
// Fused guide(LUT) + slice + apply, one block per row (256 thr x 4 px).
// LDS: y-interpolated grid ly (6KB) + transfer LUT (12KB).
// ---------------------------------------------------------------------------
__global__ void guide_slice_lut_k(const float* __restrict__ fullres,
                                  const float* __restrict__ gridc,
                                  const float2* __restrict__ lutg,
                                  const float* __restrict__ M,
                                  const float* __restrict__ Mb,
                                  const float* __restrict__ gbias,
                                  float* __restrict__ out)
{
    const int W = 1024, H = 1024;
    __shared__ float  ly[1536];                 // [z][xn][c] = [8][16][12]
    __shared__ float2 lutS[3 * LUT_NB];         // 12KB

    int h = blockIdx.x & 1023;
    int n = blockIdx.x >> 10;

    float iy = fminf(fmaxf((float)h * (16.0f / (H - 1)) - 0.5f, 0.0f), 15.0f);
    float y0f = floorf(iy);
    float wy  = iy - y0f;
    int y0 = (int)y0f, y1 = min(y0 + 1, 15);

    const float* gn = gridc + (size_t)n * 24576;
    for (int i = threadIdx.x; i < 1536; i += 256) {
        int z   = i / 192;
        int rem = i - z * 192;
        float a = gn[z * 3072 + y0 * 192 + rem];
        float b = gn[z * 3072 + y1 * 192 + rem];
        ly[i] = fmaf(wy, b - a, a);
        lutS[i] = lutg[i];
    }
    __syncthreads();

    // hoist guide matrix
    float M00 = M[0], M10 = M[3], M20 = M[6];
    float M01 = M[1], M11 = M[4], M21 = M[7];
    float M02 = M[2], M12 = M[5], M22 = M[8];
    float Mb0 = Mb[0], Mb1 = Mb[1], Mb2 = Mb[2];
    float gb  = gbias[0];

    int w0 = (int)threadIdx.x * 4;
    size_t plane = (size_t)H * W;
    size_t base  = (size_t)n * 3 * plane + (size_t)h * W + w0;
    float4 R  = *(const float4*)&fullres[base];
    float4 G  = *(const float4*)&fullres[base + plane];
    float4 Bc = *(const float4*)&fullres[base + 2 * plane];

    const float4* L = (const float4*)ly;

    float4 RR, GG, BB;
    float* rr = &RR.x; float* gg = &GG.x; float* bb = &BB.x;
    const float* rp = &R.x; const float* gp = &G.x; const float* bp = &Bc.x;

    #pragma unroll
    for (int p = 0; p < 4; ++p) {
        float r = rp[p], g = gp[p], bc = bp[p];
        int w = w0 + p;

        // ---- guide via LUT (piecewise-linear transfer, exact between knots)
        float g0 = fmaf(r, M00, fmaf(g, M10, fmaf(bc, M20, Mb0)));
        float g1 = fmaf(r, M01, fmaf(g, M11, fmaf(bc, M21, Mb1)));
        float g2 = fmaf(r, M02, fmaf(g, M12, fmaf(bc, M22, Mb2)));
        float sum = 0.0f;
        {
            float t0 = fminf(fmaxf((g0 - LUT_LO) * LUT_INV, 0.0f), LUT_NB - 1.0f);
            int i0 = (int)t0; float f0 = t0 - (float)i0;
            float2 e0 = lutS[i0];
            sum += fmaf(f0, e0.y, e0.x);
            float t1 = fminf(fmaxf((g1 - LUT_LO) * LUT_INV, 0.0f), LUT_NB - 1.0f);
            int i1 = (int)t1; float f1 = t1 - (float)i1;
            float2 e1 = lutS[LUT_NB + i1];
            sum += fmaf(f1, e1.y, e1.x);
            float t2 = fminf(fmaxf((g2 - LUT_LO) * LUT_INV, 0.0f), LUT_NB - 1.0f);
            int i2 = (int)t2; float f2 = t2 - (float)i2;
            float2 e2 = lutS[2 * LUT_NB + i2];
            sum += fmaf(f2, e2.y, e2.x);
        }
        float guide = fminf(fmaxf(sum * (1.0f / 3.0f) + gb, 0.0f), 1.0f);

        // ---- coords ----
        float ix = fminf(fmaxf((float)w * (16.0f / (W - 1)) - 0.5f, 0.0f), 15.0f);
        float iz = fminf(fmaxf(8.0f * guide - 0.5f, 0.0f), 7.0f);
        float x0f = floorf(ix), z0f = floorf(iz);
        float wx = ix - x0f, wz = iz - z0f;
        int x0 = (int)x0f; int x1 = min(x0 + 1, 15);
        int z0 = (int)z0f; int z1 = min(z0 + 1, 7);
        float mx = 1.f - wx, mz = 1.f - wz;

        int n00 = (z0 * 16 + x0) * 3, n01 = (z0 * 16 + x1) * 3;
        int n10 = (z1 * 16 + x0) * 3, n11 = (z1 * 16 + x1) * 3;
        float W00 = mz * mx, W01 = mz * wx, W10 = wz * mx, W11 = wz * wx;

        float4 A0 = {0.f, 0.f, 0.f, 0.f}, A1 = A0, A2 = A0;
        auto nodeacc = [&](int nb, float wt) {
            float4 v0 = L[nb], v1 = L[nb + 1], v2 = L[nb + 2];
            A0.x = fmaf(wt, v0.x, A0.x); A0.y = fmaf(wt, v0.y, A0.y);
            A0.z = fmaf(wt, v0.z, A0.z); A0.w = fmaf(wt, v0.w, A0.w);
            A1.x = fmaf(wt, v1.x, A1.x); A1.y = fmaf(wt, v1.y, A1.y);
            A1.z = fmaf(wt, v1.z, A1.z); A1.w = fmaf(wt, v1.w, A1.w);
            A2.x = fmaf(wt, v2.x, A2.x); A2.y = fmaf(wt, v2.y, A2.y);
            A2.z = fmaf(wt, v2.z, A2.z); A2.w = fmaf(wt, v2.w, A2.w);
        };
        nodeacc(n00, W00);
        nodeacc(n01, W01);
        nodeacc(n10, W10);
        nodeacc(n11, W11);

        rr[p] = fmaf(r, A0.x, fmaf(g, A0.y, fmaf(bc, A0.z, A0.w)));
        gg[p] = fmaf(r, A1.x, fmaf(g, A1.y, fmaf(bc, A1.z, A1.w)));
        bb[p] = fmaf(r, A2.x, fmaf(g, A2.y, fmaf(bc, A2.z, A2.w)));
    }

    *(float4*)&out[base]             = RR;
    *(float4*)&out[base + plane]     = GG;
    *(float4*)&out[base + 2 * plane] = BB;
}

// ---------------------------------------------------------------------------
extern "C" void kernel_launch(void* const* d_in, const int* in_sizes, int n_in,
                              void* d_out, int out_size, void* d_ws, size_t ws_size,
                              hipStream_t stream)
{
    const float* lowres  = (const float*)d_in[0];
    const float* fullres = (const float*)d_in[1];
    const float* sw1 = (const float*)d_in[2];  const float* sb1 = (const float*)d_in[3];
    const float* sw2 = (const float*)d_in[4];  const float* sb2 = (const float*)d_in[5];
    const float* sw3 = (const float*)d_in[6];  const float* sb3 = (const float*)d_in[7];
    const float* sw4 = (const float*)d_in[8];  const float* sb4 = (const float*)d_in[9];
    const float* gw1 = (const float*)d_in[10]; const float* gb1 = (const float*)d_in[11];
    const float* gw2 = (const float*)d_in[12]; const float* gb2 = (const float*)d_in[13];
    const float* fw3 = (const float*)d_in[14]; const float* fb3 = (const float*)d_in[15];
    const float* fw4 = (const float*)d_in[16]; const float* fb4 = (const float*)d_in[17];
    const float* fw5 = (const float*)d_in[18]; const float* fb5 = (const float*)d_in[19];
    const float* lw1 = (const float*)d_in[20]; const float* lb1 = (const float*)d_in[21];
    const float* lw2 = (const float*)d_in[22];
    const float* pw  = (const float*)d_in[23]; const float* pb  = (const float*)d_in[24];
    const float* M   = (const float*)d_in[25]; const float* Mb  = (const float*)d_in[26];
    const float* thr = (const float*)d_in[27]; const float* slp = (const float*)d_in[28];
    const float* gbias = (const float*)d_in[29];

    const int N = 2;

    float* ws    = (float*)d_ws;
    float* x1    = ws;             // HWC [2][128][128][8]  = 262144
    float* x2    = x1 + 262144;    // HWC [2][64][64][16]   = 131072
    float* x3    = x2 + 131072;    // HWC [2][32][32][32]   = 65536
    float* splat = x3 + 65536;     // HWC [2][16][16][64]   = 32768
    float* g1    = splat + 32768;  // HWC [2][8][8][64]     = 8192
    float* g2    = g1 + 8192;      // HWC [2][4][4][64]     = 2048
    float* fc3o  = g2 + 2048;      // [2][256]
    float* l1    = fc3o + 512;     // HWC [2][16][16][64]   = 32768
    float* loc   = l1 + 32768;     // HWC [2][16][16][64]   = 32768
    float* gridc = loc + 32768;    // [2][8][16][16][12]    = 49152
    float2* lutg = (float2*)(gridc + 49152);  // [3][512] float2 = 12KB

    const int B = 256;
    auto wblk = [](int total_out, int opw) {
        int waves = (total_out + opw - 1) / opw;
        return (waves * 64 + 255) / 256;
    };

    // low-res coefficient CNN (+LUT build in block 0 of conv1)
    conv1_lut_k<<<(2*128*128*8)/B, B, 0, stream>>>(lowres, sw1, sb1, thr, slp,
        x1, lutg);
    convw_hwc_k<8><<<wblk(2*64*64*16, 8), B, 0, stream>>>(x1, sw2, sb2, x2,
        N, 128, 128, 16, 64, 64, 2, 1);
    convw_hwc_k<16><<<wblk(2*32*32*32, 4), B, 0, stream>>>(x2, sw3, sb3, x3,
        N, 64, 64, 32, 32, 32, 2, 1);
    convw_hwc_k<32><<<wblk(2*16*16*64, 2), B, 0, stream>>>(x3, sw4, sb4, splat,
        N, 32, 32, 64, 16, 16, 2, 1);

    // l1 || g1 ; loc || g2
    l1_g1_k<<<(40960*64)/B, B, 0, stream>>>(splat, lw1, lb1, gw1, gb1, l1, g1);
    loc_g2_k<<<(34816*64)/B, B, 0, stream>>>(l1, lw2, g1, gw2, gb2, loc, g2);

    // fc3
    fc3_wave_k<<<wblk(N*256, 1), B, 0, stream>>>(g2, fw3, fb3, fc3o, N);

    // fc45 (per-block recompute) + fusion + pointwise grid
    fc45_fusion_k<<<(2*8*256*12)/B, B, 0, stream>>>(fc3o, fw4, fb4, fw5, fb5,
        loc, pw, pb, gridc);

    // guide(LUT) + slice + apply: one block per image row
    guide_slice_lut_k<<<N*1024, B, 0, stream>>>(fullres, gridc, lutg, M, Mb,
        gbias, (float*)d_out);
}